// Round 6
// baseline (112.306 us; speedup 1.0000x reference)
//
#include <hip/hip_runtime.h>

#define TD 10
#define NCOL 256
#define TROWS 64                       // rows per tile
#define TILES 8                        // tiles per block
#define ROWS_PER_BLOCK (TROWS * TILES) // 512

// ---- async global->LDS (16B per lane), dest = wave-uniform base + lane*16 ----
typedef const __attribute__((address_space(1))) void* as1_cvp;
typedef __attribute__((address_space(3))) void* as3_vp;
__device__ __forceinline__ void gload_lds16(const float* g, float* l) {
  __builtin_amdgcn_global_load_lds((as1_cvp)(const void*)g, (as3_vp)(void*)l, 16, 0, 0);
}

// ---- DFS fold over one level-2 subtree (256 leaves), groups of 16 at level 6 ----
// p/q indexed by ABSOLUTE level; lv pre-offset to the subtree's leaf base.
// g[k] = t6*t7*t8*t9, k = (b6<<3)|(b7<<2)|(b8<<1)|b9.
template <int LEVEL, int IDX>
__device__ __forceinline__ void fold(const float* __restrict__ lv,
                                     const float (&p)[TD], const float (&q)[TD],
                                     const float (&g)[16],
                                     float prefix, float& acc) {
  if constexpr (LEVEL == TD - 4) {
    const float* l16 = lv + 16 * IDX;
    float t = l16[0] * g[0];
#pragma unroll
    for (int k = 1; k < 16; ++k) t = fmaf(l16[k], g[k], t);
    acc = fmaf(prefix, t, acc);
  } else {
    fold<LEVEL + 1, 2 * IDX>(lv, p, q, g, prefix * q[LEVEL], acc);
    fold<LEVEL + 1, 2 * IDX + 1>(lv, p, q, g, prefix * p[LEVEL], acc);
  }
}

__global__ void __launch_bounds__(256, 2)
odt_kernel(const float* __restrict__ x, const float* __restrict__ W,
           const float* __restrict__ bias, const float* __restrict__ lv,
           float* __restrict__ out) {
  // Block-cooperative tile: 64 rows x 256 cols staged as 64 CONTIGUOUS 1KB rows
  // (sequential 64KB burst per block at DRAM — the whole point of this round).
  __shared__ float xt[TROWS * NCOL];   // 64 KB
  __shared__ float ps[4][TROWS][12];   // 12 KB partial sums (stride 12 = bank-spread)
  __shared__ float accs[4][TROWS];     // 1 KB fold partials      => 78 KB, 2 blk/CU

  const int lane = threadIdx.x & 63;
  const int wq = __builtin_amdgcn_readfirstlane(threadIdx.x >> 6);  // wave id, SGPR
  const int blockrow0 = blockIdx.x * ROWS_PER_BLOCK;

  // Stage one tile: wave wq loads rows 16wq..16wq+15, one gload_lds per row
  // (64 lanes x 16B = the full 1KB row). Per-lane SOURCE is rotated by r so the
  // stored layout xt[r][...] is rotated: unit u of row r sits at pos (u+r)&63 —
  // makes the consume ds_read_b128 hit the structural-minimum bank pattern.
  auto stage = [&](int t) {
    const int trow0 = blockrow0 + t * TROWS;
#pragma unroll
    for (int k = 0; k < 16; ++k) {
      const int r = wq * 16 + k;
      const float* src = x + (size_t)(trow0 + r) * NCOL + 4 * ((lane - r) & 63);
      gload_lds16(src, &xt[r * NCOL]);   // dest wave-uniform, lane*16 implicit
    }
  };

  stage(0);

  for (int t = 0; t < TILES; ++t) {
    __syncthreads();  // drains vmcnt -> tile t fully resident (all waves' rows)

    // ---- consume: row = lane, cols [64*wq, 64*wq+64) ; W stays s_load'd ----
    float sums[TD];
#pragma unroll
    for (int d = 0; d < TD; ++d) sums[d] = 0.0f;
#pragma unroll
    for (int i = 0; i < 16; ++i) {
      const int pos = (16 * wq + i + lane) & 63;  // rotation-swizzled position
      const float4 xv = *(const float4*)&xt[lane * NCOL + 4 * pos];
#pragma unroll
      for (int e = 0; e < 4; ++e) {
        const float xe = (&xv.x)[e];
        const int col = 64 * wq + 4 * i + e;      // wave-uniform
#pragma unroll
        for (int d = 0; d < TD; ++d)
          sums[d] = fmaf(xe, W[col * TD + d], sums[d]);
      }
    }
    {
      float* pp = &ps[wq][lane][0];
      *(float4*)(pp)     = make_float4(sums[0], sums[1], sums[2], sums[3]);
      *(float4*)(pp + 4) = make_float4(sums[4], sums[5], sums[6], sums[7]);
      *(float2*)(pp + 8) = make_float2(sums[8], sums[9]);
    }

    __syncthreads();  // ps visible to all waves; xt free for next tile

    if (t + 1 < TILES) stage(t + 1);  // issue next 64KB burst; overlaps fold

    // ---- reduce partials across the 4 waves (row = lane) ----
    float tot[TD];
#pragma unroll
    for (int d = 0; d < TD; ++d) tot[d] = bias[d];
#pragma unroll
    for (int wp = 0; wp < 4; ++wp) {
      const float* qq = &ps[wp][lane][0];
      const float4 a = *(const float4*)(qq);
      const float4 b = *(const float4*)(qq + 4);
      const float2 c = *(const float2*)(qq + 8);
      tot[0] += a.x; tot[1] += a.y; tot[2] += a.z; tot[3] += a.w;
      tot[4] += b.x; tot[5] += b.y; tot[6] += b.z; tot[7] += b.w;
      tot[8] += c.x; tot[9] += c.y;
    }

    // sigmoid
    float p[TD], q[TD];
#pragma unroll
    for (int d = 0; d < TD; ++d) {
      const float sg = 1.0f / (1.0f + __expf(-tot[d]));
      p[d] = sg;
      q[d] = 1.0f - sg;
    }

    // g[k] = t6*t7*t8*t9 for the 16 leaves of a level-6 group
    float g[16];
    {
      float hA[4], hB[4];
      hA[0] = q[6] * q[7]; hA[1] = q[6] * p[7]; hA[2] = p[6] * q[7]; hA[3] = p[6] * p[7];
      hB[0] = q[8] * q[9]; hB[1] = q[8] * p[9]; hB[2] = p[8] * q[9]; hB[3] = p[8] * p[9];
#pragma unroll
      for (int o = 0; o < 16; ++o) g[o] = hA[o >> 2] * hB[o & 3];
    }

    // ---- fold: wave wq owns level-2 subtree wq (leaves [wq*256, wq*256+256)) ----
    float acc = 0.0f;
    const float pref = ((wq & 2) ? p[0] : q[0]) * ((wq & 1) ? p[1] : q[1]);
    fold<2, 0>(lv + 256 * wq, p, q, g, pref, acc);
    accs[wq][lane] = acc;

    __syncthreads();  // accs visible (also drains stage t+1 — memory stays busy)

    if (wq == 0) {
      const float o = accs[0][lane] + accs[1][lane] + accs[2][lane] + accs[3][lane];
      out[blockrow0 + t * TROWS + lane] = o;
    }
  }
}

extern "C" void kernel_launch(void* const* d_in, const int* in_sizes, int n_in,
                              void* d_out, int out_size, void* d_ws, size_t ws_size,
                              hipStream_t stream) {
  const float* x = (const float*)d_in[0];
  const float* W = (const float*)d_in[1];
  const float* b = (const float*)d_in[2];
  const float* lv = (const float*)d_in[3];
  float* out = (float*)d_out;

  const int batch = in_sizes[0] / NCOL;        // 262144
  const int grid = batch / ROWS_PER_BLOCK;     // 512 blocks = 2/CU, 78KB LDS each
  odt_kernel<<<grid, 256, 0, stream>>>(x, W, b, lv, out);
}

// Round 7
// 106.799 us; speedup vs baseline: 1.0516x; 1.0516x over previous
//
#include <hip/hip_runtime.h>

#define TD 10
#define NCOL 256
#define HALF 128           // cols per thread (half a row)
#define GCOLS 16           // cols per prefetch group
#define NGRP (HALF / GCOLS)       // 8
#define ROWS_PER_BLOCK 128        // 256 threads = 2 threads/row

// ---- DFS fold over one level-1 subtree (512 leaves), 16-leaf terminal groups ----
// p/q indexed by ABSOLUTE level; IDX is the absolute node index at LEVEL.
// g[k] = t6*t7*t8*t9, k = (b6<<3)|(b7<<2)|(b8<<1)|b9.
template <int LEVEL, int IDX>
__device__ __forceinline__ void fold(const float* __restrict__ lv,
                                     const float (&p)[TD], const float (&q)[TD],
                                     const float (&g)[16],
                                     float prefix, float& acc) {
  if constexpr (LEVEL == TD - 4) {
    const float* l16 = lv + 16 * IDX;        // absolute leaf group
    float t = l16[0] * g[0];
#pragma unroll
    for (int k = 1; k < 16; ++k) t = fmaf(l16[k], g[k], t);
    acc = fmaf(prefix, t, acc);
  } else {
    fold<LEVEL + 1, 2 * IDX>(lv, p, q, g, prefix * q[LEVEL], acc);
    fold<LEVEL + 1, 2 * IDX + 1>(lv, p, q, g, prefix * p[LEVEL], acc);
  }
}

__global__ void __launch_bounds__(256, 8)   // force VGPR<=64 -> 8 waves/SIMD
odt_kernel(const float* __restrict__ x, const float* __restrict__ W,
           const float* __restrict__ bias, const float* __restrict__ lv,
           float* __restrict__ out) {
  // Wave roles: w = h*2 + rg.  h = col-half (wave-uniform!), rg = row-group.
  // Wave (h,rg): rows rg*64+lane, cols [h*128, h*128+128).
  __shared__ float ps[2][ROWS_PER_BLOCK][11];  // partials, stride 11 = conflict-free
  __shared__ float accs[2][ROWS_PER_BLOCK];    // per-half fold results

  const int lane = threadIdx.x & 63;
  const int w = threadIdx.x >> 6;
  const int h = __builtin_amdgcn_readfirstlane(w >> 1);  // SGPR -> W stays s_load
  const int rg = w & 1;
  const int r = rg * 64 + lane;                          // row within block
  const int row = blockIdx.x * ROWS_PER_BLOCK + r;
  const float* __restrict__ xr = x + (size_t)row * NCOL + h * HALF;

  // ping-pong register pipeline over this thread's 512B half-row
  float4 buf[2][4];
#pragma unroll
  for (int j = 0; j < 4; ++j) buf[0][j] = *(const float4*)(xr + 4 * j);

  float sums[TD];
#pragma unroll
  for (int d = 0; d < TD; ++d) sums[d] = 0.0f;

#pragma unroll
  for (int gi = 0; gi < NGRP; ++gi) {
    if (gi + 1 < NGRP) {
#pragma unroll
      for (int j = 0; j < 4; ++j)
        buf[(gi + 1) & 1][j] = *(const float4*)(xr + (gi + 1) * GCOLS + 4 * j);
    }
#pragma unroll
    for (int j = 0; j < 4; ++j) {
#pragma unroll
      for (int e = 0; e < 4; ++e) {
        const float xe = (&buf[gi & 1][j].x)[e];
        const int col = h * HALF + gi * GCOLS + 4 * j + e;  // wave-uniform
#pragma unroll
        for (int d = 0; d < TD; ++d)
          sums[d] = fmaf(xe, W[col * TD + d], sums[d]);     // W -> s_load
      }
    }
  }

  // publish partials (stride-11 rows: lanes hit 32 distinct banks)
#pragma unroll
  for (int d = 0; d < TD; ++d) ps[h][r][d] = sums[d];
  __syncthreads();

  // combine halves + sigmoid (duplicated across the pair — 60 cheap ops)
  float p[TD], q[TD];
#pragma unroll
  for (int d = 0; d < TD; ++d) {
    const float tot = bias[d] + sums[d] + ps[h ^ 1][r][d];
    const float sg = 1.0f / (1.0f + __expf(-tot));
    p[d] = sg;
    q[d] = 1.0f - sg;
  }

  // g[k] = t6*t7*t8*t9 products for a 16-leaf group
  float g[16];
  {
    float hA[4], hB[4];
    hA[0] = q[6] * q[7]; hA[1] = q[6] * p[7]; hA[2] = p[6] * q[7]; hA[3] = p[6] * p[7];
    hB[0] = q[8] * q[9]; hB[1] = q[8] * p[9]; hB[2] = p[8] * q[9]; hB[3] = p[8] * p[9];
#pragma unroll
    for (int o = 0; o < 16; ++o) g[o] = hA[o >> 2] * hB[o & 3];
  }

  // each col-half folds one level-1 subtree (~620 ops); wave-uniform branch
  float acc = 0.0f;
  if (h == 0) fold<1, 0>(lv, p, q, g, q[0], acc);
  else        fold<1, 1>(lv, p, q, g, p[0], acc);
  accs[h][r] = acc;
  __syncthreads();

  if (h == 0)                                   // waves 0,1: coalesced 256B stores
    out[row] = accs[0][r] + accs[1][r];
}

extern "C" void kernel_launch(void* const* d_in, const int* in_sizes, int n_in,
                              void* d_out, int out_size, void* d_ws, size_t ws_size,
                              hipStream_t stream) {
  const float* x = (const float*)d_in[0];
  const float* W = (const float*)d_in[1];
  const float* b = (const float*)d_in[2];
  const float* lv = (const float*)d_in[3];
  float* out = (float*)d_out;

  const int batch = in_sizes[0] / NCOL;          // 262144
  const int grid = batch / ROWS_PER_BLOCK;       // 2048 blocks = 8/CU = 32 waves/CU
  odt_kernel<<<grid, 256, 0, stream>>>(x, W, b, lv, out);
}

// Round 8
// 98.094 us; speedup vs baseline: 1.1449x; 1.0887x over previous
//
#include <hip/hip_runtime.h>

#define TD 10
#define NCOL 256
#define HALF 128                  // cols per thread (half a row)
#define GCOLS 16                  // cols per group (4 float4)
#define ROWS_PER_BLOCK 128        // 256 threads = 2 threads/row

// ---- DFS fold over one level-1 subtree (512 leaves), 16-leaf terminal groups ----
// p/q indexed by ABSOLUTE level; IDX is the absolute node index at LEVEL.
// g[k] = t6*t7*t8*t9, k = (b6<<3)|(b7<<2)|(b8<<1)|b9.
template <int LEVEL, int IDX>
__device__ __forceinline__ void fold(const float* __restrict__ lv,
                                     const float (&p)[TD], const float (&q)[TD],
                                     const float (&g)[16],
                                     float prefix, float& acc) {
  if constexpr (LEVEL == TD - 4) {
    const float* l16 = lv + 16 * IDX;
    float t = l16[0] * g[0];
#pragma unroll
    for (int k = 1; k < 16; ++k) t = fmaf(l16[k], g[k], t);
    acc = fmaf(prefix, t, acc);
  } else {
    fold<LEVEL + 1, 2 * IDX>(lv, p, q, g, prefix * q[LEVEL], acc);
    fold<LEVEL + 1, 2 * IDX + 1>(lv, p, q, g, prefix * p[LEVEL], acc);
  }
}

__global__ void __launch_bounds__(256, 8)   // 8 waves/SIMD; code sized to fit 64 VGPR
odt_kernel(const float* __restrict__ x, const float* __restrict__ W,
           const float* __restrict__ bias, const float* __restrict__ lv,
           float* __restrict__ out) {
  // Wave roles: w = threadIdx.x>>6; h = w>>1 (col-half, wave-uniform SGPR),
  // rg = w&1 (row-group). Wave (h,rg): rows rg*64+lane, cols [h*128, h*128+128).
  __shared__ float ps[2][ROWS_PER_BLOCK][11];  // partials, stride 11 = conflict-free
  __shared__ float accs[2][ROWS_PER_BLOCK];

  const int lane = threadIdx.x & 63;
  const int w = threadIdx.x >> 6;
  const int h = __builtin_amdgcn_readfirstlane(w >> 1);  // SGPR -> W stays s_load
  const int r = (w & 1) * 64 + lane;                     // row within block
  const int row = blockIdx.x * ROWS_PER_BLOCK + r;
  const float* __restrict__ xr = x + (size_t)row * NCOL + h * HALF;

  float sums[TD];
#pragma unroll
  for (int d = 0; d < TD; ++d) sums[d] = 0.0f;

  // NO arrays, NO address-taking on vector regs — spill-proof by construction.
  float4 A0, A1, A2, A3, B0, B1, B2, B3;

#define LOADG(V0, V1, V2, V3, G)                                   \
  V0 = *(const float4*)(xr + (G) * GCOLS + 0);                     \
  V1 = *(const float4*)(xr + (G) * GCOLS + 4);                     \
  V2 = *(const float4*)(xr + (G) * GCOLS + 8);                     \
  V3 = *(const float4*)(xr + (G) * GCOLS + 12);

  auto fmacol = [&](float xe, int col) {
#pragma unroll
    for (int d = 0; d < TD; ++d)
      sums[d] = fmaf(xe, W[col * TD + d], sums[d]);  // col wave-uniform -> s_load
  };
#define CONS4(V, CB)                                               \
  fmacol(V.x, (CB) + 0); fmacol(V.y, (CB) + 1);                    \
  fmacol(V.z, (CB) + 2); fmacol(V.w, (CB) + 3);
#define CONSG(V0, V1, V2, V3, G)                                   \
  CONS4(V0, h * HALF + (G) * GCOLS + 0)                            \
  CONS4(V1, h * HALF + (G) * GCOLS + 4)                            \
  CONS4(V2, h * HALF + (G) * GCOLS + 8)                            \
  CONS4(V3, h * HALF + (G) * GCOLS + 12)

  // software pipeline: next group's 4 loads in flight across current's 160 FMAs
  LOADG(A0, A1, A2, A3, 0)
  LOADG(B0, B1, B2, B3, 1)
  CONSG(A0, A1, A2, A3, 0)
  LOADG(A0, A1, A2, A3, 2)
  CONSG(B0, B1, B2, B3, 1)
  LOADG(B0, B1, B2, B3, 3)
  CONSG(A0, A1, A2, A3, 2)
  LOADG(A0, A1, A2, A3, 4)
  CONSG(B0, B1, B2, B3, 3)
  LOADG(B0, B1, B2, B3, 5)
  CONSG(A0, A1, A2, A3, 4)
  LOADG(A0, A1, A2, A3, 6)
  CONSG(B0, B1, B2, B3, 5)
  LOADG(B0, B1, B2, B3, 7)
  CONSG(A0, A1, A2, A3, 6)
  CONSG(B0, B1, B2, B3, 7)
#undef LOADG
#undef CONS4
#undef CONSG

  // publish partials (stride-11 rows: lanes hit all 32 banks evenly)
#pragma unroll
  for (int d = 0; d < TD; ++d) ps[h][r][d] = sums[d];
  __syncthreads();

  // combine halves + sigmoid (duplicated across the pair — cheap)
  float p[TD], q[TD];
#pragma unroll
  for (int d = 0; d < TD; ++d) {
    const float tot = bias[d] + sums[d] + ps[h ^ 1][r][d];
    const float sg = 1.0f / (1.0f + __expf(-tot));
    p[d] = sg;
    q[d] = 1.0f - sg;
  }

  // g[k] = t6*t7*t8*t9 products for a 16-leaf group
  float g[16];
  {
    float hA[4], hB[4];
    hA[0] = q[6] * q[7]; hA[1] = q[6] * p[7]; hA[2] = p[6] * q[7]; hA[3] = p[6] * p[7];
    hB[0] = q[8] * q[9]; hB[1] = q[8] * p[9]; hB[2] = p[8] * q[9]; hB[3] = p[8] * p[9];
#pragma unroll
    for (int o = 0; o < 16; ++o) g[o] = hA[o >> 2] * hB[o & 3];
  }

  // each col-half folds one level-1 subtree (~690 ops); h is SGPR -> no divergence
  float acc = 0.0f;
  if (h == 0) fold<1, 0>(lv, p, q, g, q[0], acc);
  else        fold<1, 1>(lv, p, q, g, p[0], acc);
  accs[h][r] = acc;
  __syncthreads();

  if (h == 0)                                   // waves 0,1: coalesced stores
    out[row] = accs[0][r] + accs[1][r];
}

extern "C" void kernel_launch(void* const* d_in, const int* in_sizes, int n_in,
                              void* d_out, int out_size, void* d_ws, size_t ws_size,
                              hipStream_t stream) {
  const float* x = (const float*)d_in[0];
  const float* W = (const float*)d_in[1];
  const float* b = (const float*)d_in[2];
  const float* lv = (const float*)d_in[3];
  float* out = (float*)d_out;

  const int batch = in_sizes[0] / NCOL;          // 262144
  const int grid = batch / ROWS_PER_BLOCK;       // 2048 blocks = 8/CU = 32 waves/CU
  odt_kernel<<<grid, 256, 0, stream>>>(x, W, b, lv, out);
}